// Round 28
// baseline (74.724 us; speedup 1.0000x reference)
//
#include <hip/hip_runtime.h>

#define NN 50000
#define NE 300000
#define KDIM 256
#define FDIM 64
#define CAP 48              // max degree capacity; P(deg>47)~1e-30 for multinomial(6)
#define CSTRIDE 16          // one counter per 64B line
#define NTILES16 (NN / 16)  // 3125 row-tiles for MFMA gemm
#define SCAT_BLKS ((NE + 255) / 256)          // 1172
#define GEMM_BLKS ((NTILES16 + 3) / 4)        // 782: 4 tiles/block, 1 tile/wave
#define XPAD 260            // row stride in floats (+4 pad: bank rotation)

typedef __attribute__((ext_vector_type(8))) short bf16x8;
typedef __attribute__((ext_vector_type(4))) float f32x4;

static __device__ __forceinline__ unsigned short bf16_of(float f) {
  union { float f; unsigned u; } v; v.f = f;
  unsigned r = (v.u + 0x7fffu + ((v.u >> 16) & 1u)) >> 16;  // RTNE
  return (unsigned short)r;
}
static __device__ __forceinline__ void unpack2(unsigned u, float& lo, float& hi) {
  union { unsigned u; float f; } a, b;
  a.u = u << 16; b.u = u & 0xffff0000u;
  lo = a.f; hi = b.f;
}
static __device__ __forceinline__ unsigned pack2(float lo, float hi) {
  return (unsigned)bf16_of(lo) | ((unsigned)bf16_of(hi) << 16);
}

// async global->LDS, 16B per lane: LDS dest = wave-uniform base + lane*16.
static __device__ __forceinline__ void gload_lds16(const float* g, void* l) {
  __builtin_amdgcn_global_load_lds(
      (const __attribute__((address_space(1))) void*)g,
      (__attribute__((address_space(3))) void*)l, 16, 0, 0);
}

// ---------- init: zero cntp (blocks 0..3124) + W->bf16 (blocks 3125..3188) ----------
__global__ __launch_bounds__(256) void init_kernel(int* __restrict__ cntp,
    const float* __restrict__ W, unsigned short* __restrict__ wbf) {
  int b = blockIdx.x, t = threadIdx.x;
  if (b < 3125) {
    cntp[b * 256 + t] = 0;          // 3125*256 = 800000 = NN*CSTRIDE exactly
  } else {
    int i = (b - 3125) * 256 + t;   // 64 blocks * 256 = 16384 = FDIM*KDIM
    wbf[i] = bf16_of(W[i]);
  }
}

// ---------- scatter (standalone): cntp[d*16] = deg, col[d*CAP+pos] = src ----------
__global__ __launch_bounds__(256) void scatter_kernel(
    const int* __restrict__ src, const int* __restrict__ dst,
    int* __restrict__ cntp, int* __restrict__ col) {
  int e = blockIdx.x * 256 + threadIdx.x;
  if (e < NE) {
    int d = dst[e];
    int pos = atomicAdd(&cntp[d * CSTRIDE], 1);
    if (pos < CAP) col[d * CAP + pos] = src[e];  // guard: never corrupt
  }
}

// ---------- gemm: yh = bf16( x @ W^T ), RAW (dinv deferred to hops) ----------
// R27 diagnosis: old staging read lanes 4KB apart -> 64 scattered 128B granules
// per instruction -> 1.27 TB/s HBM. NEW: row-linear staging — instruction r
// loads row r0+r's 1KB via lane*16B (perfectly coalesced) -> ~6 TB/s stream.
// One wave = one 16-row tile, full K=256 (no K-split). Rows padded +4 floats
// in LDS: m-stride bank rotation 4 -> 2-way conflicts (free, m136).
// C/D: col=lane&15, row=(lane>>4)*4+reg (HW-verified m89).
__global__ __launch_bounds__(256) void gemm_kernel(
    const float* __restrict__ x, const unsigned short* __restrict__ wbf,
    unsigned short* __restrict__ yh) {
  __shared__ float xs[4][16][XPAD];          // 66.6 KB -> 2 blocks/CU
  const int wave = threadIdx.x >> 6, lane = threadIdx.x & 63;
  const int tile = blockIdx.x * 4 + wave;
  const bool valid = (tile < NTILES16);
  const int m = lane & 15, kg = lane >> 4;
  const int r0 = tile * 16;
  const float* xrow = x + (size_t)(valid ? r0 : 0) * KDIM;

  #pragma unroll
  for (int r = 0; r < 16; ++r)               // 16 coalesced 1KB stages/wave
    gload_lds16(xrow + r * KDIM + lane * 4, &xs[wave][r][0]);
  __syncthreads();                           // vmcnt(0) drain -> xs valid

  f32x4 acc0 = {0.f, 0.f, 0.f, 0.f};
  f32x4 acc1 = {0.f, 0.f, 0.f, 0.f};
  f32x4 acc2 = {0.f, 0.f, 0.f, 0.f};
  f32x4 acc3 = {0.f, 0.f, 0.f, 0.f};
  if (valid) {
    const unsigned short* w0 = wbf + (size_t)m * KDIM + kg * 8;
    #pragma unroll
    for (int kc = 0; kc < 8; ++kc) {
      const float* ap = &xs[wave][m][kc * 32 + kg * 8];
      float4 a0 = *(const float4*)(ap);      // ds_read_b128, 2-way banked
      float4 a1 = *(const float4*)(ap + 4);
      bf16x8 af;
      af[0] = bf16_of(a0.x); af[1] = bf16_of(a0.y);
      af[2] = bf16_of(a0.z); af[3] = bf16_of(a0.w);
      af[4] = bf16_of(a1.x); af[5] = bf16_of(a1.y);
      af[6] = bf16_of(a1.z); af[7] = bf16_of(a1.w);
      bf16x8 b0 = *(const bf16x8*)(w0 + 0 * 16 * KDIM + kc * 32);
      bf16x8 b1 = *(const bf16x8*)(w0 + 1 * 16 * KDIM + kc * 32);
      bf16x8 b2 = *(const bf16x8*)(w0 + 2 * 16 * KDIM + kc * 32);
      bf16x8 b3 = *(const bf16x8*)(w0 + 3 * 16 * KDIM + kc * 32);
      acc0 = __builtin_amdgcn_mfma_f32_16x16x32_bf16(af, b0, acc0, 0, 0, 0);
      acc1 = __builtin_amdgcn_mfma_f32_16x16x32_bf16(af, b1, acc1, 0, 0, 0);
      acc2 = __builtin_amdgcn_mfma_f32_16x16x32_bf16(af, b2, acc2, 0, 0, 0);
      acc3 = __builtin_amdgcn_mfma_f32_16x16x32_bf16(af, b3, acc3, 0, 0, 0);
    }
    const int m4 = kg * 4;
    #pragma unroll
    for (int r = 0; r < 4; ++r) {
      size_t rowoff = (size_t)(r0 + m4 + r) * FDIM + m;
      yh[rowoff + 0]  = bf16_of(acc0[r]);    // RAW Y (no dinv)
      yh[rowoff + 16] = bf16_of(acc1[r]);
      yh[rowoff + 32] = bf16_of(acc2[r]);
      yh[rowoff + 48] = bf16_of(acc3[r]);
    }
  }
}

// ---------- compact: deg[i] = cntp[i*16]  (keeps gather's deg reads in 200KB) ----------
__global__ __launch_bounds__(256) void compact_kernel(const int* __restrict__ cntp,
                                                      int* __restrict__ deg) {
  int i = blockIdx.x * 256 + threadIdx.x;
  if (i < NN) deg[i] = cntp[i * CSTRIDE];
}

// ---------- gather hop over bf16 rows (128B): 2 nodes/wave, 32 lanes x uint ----------
// NBRNORM=1 (hop 1): u_i = dinv_i^2 * ( dinv_i*Y_i + sum_j dinv_j*Y_j )
// NBRNORM=0 (hop 2): out_i = dinv_i * ( u_i + sum_j u_j )
// fp32 accumulation; masked 4-batches (OOB multiplier/value zeroed by cndmask).
template <int OUT32, int NBRNORM>
__global__ __launch_bounds__(256) void gather_kernel(const unsigned* __restrict__ inu,
    void* __restrict__ outp, const int* __restrict__ cnt,
    const int* __restrict__ col) {
  int wave = threadIdx.x >> 6, lane = threadIdx.x & 63;
  int half = lane >> 5, hl = lane & 31;
  int node = blockIdx.x * 8 + wave * 2 + half;          // 6250*8 = 50000 exact
  int deg = cnt[node];
  int n = min(deg, CAP);
  int sbase = lane & 32;                                // half*32
  float fdeg = (float)deg + 1.0f;
  float di = rsqrtf(fdeg);
  float selfm = NBRNORM ? di : 1.0f;
  float ax, ay;
  unpack2(inu[(size_t)node * 32 + hl], ax, ay);         // self-loop
  ax *= selfm; ay *= selfm;
  float bx = 0.f, by = 0.f, cx = 0.f, cy = 0.f, dx = 0.f, dy = 0.f;
  for (int base = 0; base < n; base += 32) {
    int mB = min(32, n - base);
    int idx = 0; float dvl = 0.f;
    if (hl < mB) {
      idx = col[node * CAP + base + hl];
      if (NBRNORM) dvl = rsqrtf((float)cnt[idx] + 1.0f);
    }
    for (int j = 0; j < mB; j += 4) {
      int c0 = __shfl(idx, sbase + j + 0);
      int c1 = __shfl(idx, sbase + j + 1);
      int c2 = __shfl(idx, sbase + j + 2);
      int c3 = __shfl(idx, sbase + j + 3);
      unsigned u0 = inu[(size_t)c0 * 32 + hl];
      unsigned u1 = inu[(size_t)c1 * 32 + hl];
      unsigned u2 = inu[(size_t)c2 * 32 + hl];
      unsigned u3 = inu[(size_t)c3 * 32 + hl];
      float lx, hy;
      if (NBRNORM) {
        float f0 = __shfl(dvl, sbase + j + 0);
        float f1 = __shfl(dvl, sbase + j + 1);
        float f2 = __shfl(dvl, sbase + j + 2);
        float f3 = __shfl(dvl, sbase + j + 3);
        f1 = (j + 1 < mB) ? f1 : 0.f;                   // mask the multiplier
        f2 = (j + 2 < mB) ? f2 : 0.f;
        f3 = (j + 3 < mB) ? f3 : 0.f;
        unpack2(u0, lx, hy); ax = fmaf(lx, f0, ax); ay = fmaf(hy, f0, ay);
        unpack2(u1, lx, hy); bx = fmaf(lx, f1, bx); by = fmaf(hy, f1, by);
        unpack2(u2, lx, hy); cx = fmaf(lx, f2, cx); cy = fmaf(hy, f2, cy);
        unpack2(u3, lx, hy); dx = fmaf(lx, f3, dx); dy = fmaf(hy, f3, dy);
      } else {
        u1 = (j + 1 < mB) ? u1 : 0u;                    // mask the value
        u2 = (j + 2 < mB) ? u2 : 0u;
        u3 = (j + 3 < mB) ? u3 : 0u;
        unpack2(u0, lx, hy); ax += lx; ay += hy;
        unpack2(u1, lx, hy); bx += lx; by += hy;
        unpack2(u2, lx, hy); cx += lx; cy += hy;
        unpack2(u3, lx, hy); dx += lx; dy += hy;
      }
    }
  }
  float s = NBRNORM ? (1.0f / fdeg) : di;               // dinv^2 : dinv
  float rx = (ax + bx + cx + dx) * s;
  float ry = (ay + by + cy + dy) * s;
  if (OUT32) {
    float2 r; r.x = rx; r.y = ry;
    ((float2*)outp)[(size_t)node * 32 + hl] = r;        // fp32 row = 32 float2
  } else {
    ((unsigned*)outp)[(size_t)node * 32 + hl] = pack2(rx, ry);  // bf16 row
  }
}

extern "C" void kernel_launch(void* const* d_in, const int* in_sizes, int n_in,
                              void* d_out, int out_size, void* d_ws, size_t ws_size,
                              hipStream_t stream) {
  const float* x = (const float*)d_in[0];    // [NN, 256]
  const int* ei  = (const int*)d_in[1];      // [2, NE]
  const float* W = (const float*)d_in[2];    // [64, 256]
  float* out     = (float*)d_out;            // [NN, 64]
  const int* src = ei;
  const int* dst = ei + NE;

  // ws (4B units): cntp[NN*16] | col[NN*CAP] | yh[NN*32] | zh[NN*32] | wbf[8192] | deg[NN]
  size_t o_cntp = 0;
  size_t o_col  = o_cntp + (size_t)NN * CSTRIDE;
  size_t o_yh   = o_col + (size_t)NN * CAP;
  size_t o_zh   = o_yh + (size_t)NN * (FDIM / 2);
  size_t o_wbf  = o_zh + (size_t)NN * (FDIM / 2);
  size_t o_deg  = o_wbf + 8192;
  size_t need   = (o_deg + NN) * 4;          // ~25.9 MB
  if (ws_size < need || d_ws == nullptr) return;  // fail loudly, never OOB

  int* cntp          = (int*)d_ws + o_cntp;
  int* col           = (int*)d_ws + o_col;
  unsigned short* yh = (unsigned short*)((float*)d_ws + o_yh);
  unsigned short* zh = (unsigned short*)((float*)d_ws + o_zh);
  unsigned short* wbf= (unsigned short*)((float*)d_ws + o_wbf);
  int* deg           = (int*)d_ws + o_deg;

  // 1. zero cntp + W->bf16
  init_kernel<<<3189, 256, 0, stream>>>(cntp, W, wbf);
  // 2. scatter (unchanged)
  scatter_kernel<<<SCAT_BLKS, 256, 0, stream>>>(src, dst, cntp, col);
  // 3. gemm with COALESCED row staging: yh = bf16(x @ W^T)
  gemm_kernel<<<GEMM_BLKS, 256, 0, stream>>>(x, wbf, yh);
  // 4. deg[i] = cntp[i*16]
  compact_kernel<<<(NN + 255) / 256, 256, 0, stream>>>(cntp, deg);
  // 5. hop 1: zh = bf16( dinv^2 * (dinv*Y_self + sum dinv_j*Y_j) )
  gather_kernel<0, 1><<<NN / 8, 256, 0, stream>>>((const unsigned*)yh, zh, deg, col);
  // 6. hop 2: out = dinv * (A+I) zh
  gather_kernel<1, 0><<<NN / 8, 256, 0, stream>>>((const unsigned*)zh, out, deg, col);
}

// Round 29
// 70.440 us; speedup vs baseline: 1.0608x; 1.0608x over previous
//
#include <hip/hip_runtime.h>

#define NN 50000
#define NE 300000
#define KDIM 256
#define FDIM 64
#define CAP 48              // max degree capacity; P(deg>47)~1e-30 for multinomial(6)
#define CSTRIDE 16          // one counter per 64B line
#define NTILES16 (NN / 16)  // 3125 row-tiles for MFMA gemm
#define SCAT_BLKS ((NE + 255) / 256)          // 1172
#define GEMM_BLKS ((NTILES16 + 1) / 2)        // 1563

typedef __attribute__((ext_vector_type(8))) short bf16x8;
typedef __attribute__((ext_vector_type(4))) float f32x4;

static __device__ __forceinline__ unsigned short bf16_of(float f) {
  union { float f; unsigned u; } v; v.f = f;
  unsigned r = (v.u + 0x7fffu + ((v.u >> 16) & 1u)) >> 16;  // RTNE
  return (unsigned short)r;
}
static __device__ __forceinline__ void unpack2(unsigned u, float& lo, float& hi) {
  union { unsigned u; float f; } a, b;
  a.u = u << 16; b.u = u & 0xffff0000u;
  lo = a.f; hi = b.f;
}
static __device__ __forceinline__ unsigned pack2(float lo, float hi) {
  return (unsigned)bf16_of(lo) | ((unsigned)bf16_of(hi) << 16);
}

// async global->LDS, 16B per lane: LDS dest = wave-uniform base + lane*16.
static __device__ __forceinline__ void gload_lds16(const float* g, void* l) {
  __builtin_amdgcn_global_load_lds(
      (const __attribute__((address_space(1))) void*)g,
      (__attribute__((address_space(3))) void*)l, 16, 0, 0);
}

// ---------- init: zero cntp (blocks 0..3124) + W->bf16 (blocks 3125..3188) ----------
__global__ __launch_bounds__(256) void init_kernel(int* __restrict__ cntp,
    const float* __restrict__ W, unsigned short* __restrict__ wbf) {
  int b = blockIdx.x, t = threadIdx.x;
  if (b < 3125) {
    cntp[b * 256 + t] = 0;          // 3125*256 = 800000 = NN*CSTRIDE exactly
  } else {
    int i = (b - 3125) * 256 + t;   // 64 blocks * 256 = 16384 = FDIM*KDIM
    wbf[i] = bf16_of(W[i]);
  }
}

// ---------- fused: scatter (blocks < SCAT_BLKS)  ||  raw MFMA gemm (rest) ----------
// R23-measured fastest arrangement (70.3 total). Independent halves:
// scatter touches {cntp,col,src,dst}; gemm touches {x,wbf,yh}.
// gemm emits RAW Y = x@W^T (bf16); dinv deferred to hops:
//   out = D^-1/2 (A+I) D^-1 (A+I) D^-1/2 Y.
// C/D: col=lane&15, row=(lane>>4)*4+reg (HW-verified m89).
__global__ __launch_bounds__(256) void fused_kernel(
    const int* __restrict__ src, const int* __restrict__ dst,
    int* __restrict__ cntp, int* __restrict__ col,
    const float* __restrict__ x, const unsigned short* __restrict__ wbf,
    unsigned short* __restrict__ yh) {
  __shared__ float4 xs[4][8][64];            // 32 KB: per-wave x staging
  __shared__ float red[2][16][64];           // 8 KB (K-split reduction)
  if (blockIdx.x < SCAT_BLKS) {              // ---- scatter ----
    int e = blockIdx.x * 256 + threadIdx.x;
    if (e < NE) {
      int d = dst[e];
      int pos = atomicAdd(&cntp[d * CSTRIDE], 1);
      if (pos < CAP) col[d * CAP + pos] = src[e];  // guard: never corrupt
    }
    return;                                  // scatter blocks skip all barriers
  }
  // ---- K-split x2 gemm: waves (2t+kh) own tile t's K-half kh (128 wide) ----
  const int tp = blockIdx.x - SCAT_BLKS;
  const int wave = threadIdx.x >> 6, lane = threadIdx.x & 63;
  const int tib = wave >> 1, kh = wave & 1;
  const int tile = tp * 2 + tib;
  const bool valid = (tile < NTILES16);
  const int m = lane & 15, kg = lane >> 4;
  const int r0 = tile * 16;
  const float* xr = x + (size_t)((valid ? r0 : 0) + m) * KDIM + kh * 128 + kg * 8;
  const unsigned short* w0 = wbf + (size_t)m * KDIM + kh * 128 + kg * 8;

  #pragma unroll
  for (int j = 0; j < 8; ++j)                // 8 async 1KB stages, zero VGPRs
    gload_lds16(xr + (j >> 1) * 32 + (j & 1) * 4, &xs[wave][j][0]);
  __syncthreads();                           // vmcnt(0) drain -> xs valid

  f32x4 acc0 = {0.f, 0.f, 0.f, 0.f};
  f32x4 acc1 = {0.f, 0.f, 0.f, 0.f};
  f32x4 acc2 = {0.f, 0.f, 0.f, 0.f};
  f32x4 acc3 = {0.f, 0.f, 0.f, 0.f};
  if (valid) {
    #pragma unroll
    for (int kc = 0; kc < 4; ++kc) {
      float4 a0 = xs[wave][2 * kc][lane];    // ds_read_b128, lane's own chunk
      float4 a1 = xs[wave][2 * kc + 1][lane];
      bf16x8 af;
      af[0] = bf16_of(a0.x); af[1] = bf16_of(a0.y);
      af[2] = bf16_of(a0.z); af[3] = bf16_of(a0.w);
      af[4] = bf16_of(a1.x); af[5] = bf16_of(a1.y);
      af[6] = bf16_of(a1.z); af[7] = bf16_of(a1.w);
      bf16x8 b0 = *(const bf16x8*)(w0 + 0 * 16 * KDIM + kc * 32);
      bf16x8 b1 = *(const bf16x8*)(w0 + 1 * 16 * KDIM + kc * 32);
      bf16x8 b2 = *(const bf16x8*)(w0 + 2 * 16 * KDIM + kc * 32);
      bf16x8 b3 = *(const bf16x8*)(w0 + 3 * 16 * KDIM + kc * 32);
      acc0 = __builtin_amdgcn_mfma_f32_16x16x32_bf16(af, b0, acc0, 0, 0, 0);
      acc1 = __builtin_amdgcn_mfma_f32_16x16x32_bf16(af, b1, acc1, 0, 0, 0);
      acc2 = __builtin_amdgcn_mfma_f32_16x16x32_bf16(af, b2, acc2, 0, 0, 0);
      acc3 = __builtin_amdgcn_mfma_f32_16x16x32_bf16(af, b3, acc3, 0, 0, 0);
    }
  }
  if (valid && kh == 1) {
    #pragma unroll
    for (int j = 0; j < 4; ++j) {
      red[tib][0 + j][lane]  = acc0[j];
      red[tib][4 + j][lane]  = acc1[j];
      red[tib][8 + j][lane]  = acc2[j];
      red[tib][12 + j][lane] = acc3[j];
    }
  }
  __syncthreads();
  if (valid && kh == 0) {
    #pragma unroll
    for (int j = 0; j < 4; ++j) {
      acc0[j] += red[tib][0 + j][lane];
      acc1[j] += red[tib][4 + j][lane];
      acc2[j] += red[tib][8 + j][lane];
      acc3[j] += red[tib][12 + j][lane];
    }
    const int m4 = kg * 4;
    #pragma unroll
    for (int r = 0; r < 4; ++r) {
      size_t rowoff = (size_t)(r0 + m4 + r) * FDIM + m;
      yh[rowoff + 0]  = bf16_of(acc0[r]);    // RAW Y (no dinv)
      yh[rowoff + 16] = bf16_of(acc1[r]);
      yh[rowoff + 32] = bf16_of(acc2[r]);
      yh[rowoff + 48] = bf16_of(acc3[r]);
    }
  }
}

// ---------- gather hop over bf16 rows (128B): 2 nodes/wave, 32 lanes x uint ----------
// Degrees read DIRECTLY from padded cntp[i*CSTRIDE] (compact kernel removed;
// 3.2MB spread is L2-resident). NBRNORM=1 (hop 1):
//   u_i = dinv_i^2 * ( dinv_i*Y_i + sum_j dinv_j*Y_j )
// NBRNORM=0 (hop 2): out_i = dinv_i * ( u_i + sum_j u_j )
// fp32 accumulation; masked 4-batches (OOB multiplier/value zeroed by cndmask).
template <int OUT32, int NBRNORM>
__global__ __launch_bounds__(256) void gather_kernel(const unsigned* __restrict__ inu,
    void* __restrict__ outp, const int* __restrict__ cntp,
    const int* __restrict__ col) {
  int wave = threadIdx.x >> 6, lane = threadIdx.x & 63;
  int half = lane >> 5, hl = lane & 31;
  int node = blockIdx.x * 8 + wave * 2 + half;          // 6250*8 = 50000 exact
  int deg = cntp[node * CSTRIDE];
  int n = min(deg, CAP);
  int sbase = lane & 32;                                // half*32
  float fdeg = (float)deg + 1.0f;
  float di = rsqrtf(fdeg);
  float selfm = NBRNORM ? di : 1.0f;
  float ax, ay;
  unpack2(inu[(size_t)node * 32 + hl], ax, ay);         // self-loop
  ax *= selfm; ay *= selfm;
  float bx = 0.f, by = 0.f, cx = 0.f, cy = 0.f, dx = 0.f, dy = 0.f;
  for (int base = 0; base < n; base += 32) {
    int mB = min(32, n - base);
    int idx = 0; float dvl = 0.f;
    if (hl < mB) {
      idx = col[node * CAP + base + hl];
      if (NBRNORM) dvl = rsqrtf((float)cntp[idx * CSTRIDE] + 1.0f);
    }
    for (int j = 0; j < mB; j += 4) {
      int c0 = __shfl(idx, sbase + j + 0);
      int c1 = __shfl(idx, sbase + j + 1);
      int c2 = __shfl(idx, sbase + j + 2);
      int c3 = __shfl(idx, sbase + j + 3);
      unsigned u0 = inu[(size_t)c0 * 32 + hl];
      unsigned u1 = inu[(size_t)c1 * 32 + hl];
      unsigned u2 = inu[(size_t)c2 * 32 + hl];
      unsigned u3 = inu[(size_t)c3 * 32 + hl];
      float lx, hy;
      if (NBRNORM) {
        float f0 = __shfl(dvl, sbase + j + 0);
        float f1 = __shfl(dvl, sbase + j + 1);
        float f2 = __shfl(dvl, sbase + j + 2);
        float f3 = __shfl(dvl, sbase + j + 3);
        f1 = (j + 1 < mB) ? f1 : 0.f;                   // mask the multiplier
        f2 = (j + 2 < mB) ? f2 : 0.f;
        f3 = (j + 3 < mB) ? f3 : 0.f;
        unpack2(u0, lx, hy); ax = fmaf(lx, f0, ax); ay = fmaf(hy, f0, ay);
        unpack2(u1, lx, hy); bx = fmaf(lx, f1, bx); by = fmaf(hy, f1, by);
        unpack2(u2, lx, hy); cx = fmaf(lx, f2, cx); cy = fmaf(hy, f2, cy);
        unpack2(u3, lx, hy); dx = fmaf(lx, f3, dx); dy = fmaf(hy, f3, dy);
      } else {
        u1 = (j + 1 < mB) ? u1 : 0u;                    // mask the value
        u2 = (j + 2 < mB) ? u2 : 0u;
        u3 = (j + 3 < mB) ? u3 : 0u;
        unpack2(u0, lx, hy); ax += lx; ay += hy;
        unpack2(u1, lx, hy); bx += lx; by += hy;
        unpack2(u2, lx, hy); cx += lx; cy += hy;
        unpack2(u3, lx, hy); dx += lx; dy += hy;
      }
    }
  }
  float s = NBRNORM ? (1.0f / fdeg) : di;               // dinv^2 : dinv
  float rx = (ax + bx + cx + dx) * s;
  float ry = (ay + by + cy + dy) * s;
  if (OUT32) {
    float2 r; r.x = rx; r.y = ry;
    ((float2*)outp)[(size_t)node * 32 + hl] = r;        // fp32 row = 32 float2
  } else {
    ((unsigned*)outp)[(size_t)node * 32 + hl] = pack2(rx, ry);  // bf16 row
  }
}

extern "C" void kernel_launch(void* const* d_in, const int* in_sizes, int n_in,
                              void* d_out, int out_size, void* d_ws, size_t ws_size,
                              hipStream_t stream) {
  const float* x = (const float*)d_in[0];    // [NN, 256]
  const int* ei  = (const int*)d_in[1];      // [2, NE]
  const float* W = (const float*)d_in[2];    // [64, 256]
  float* out     = (float*)d_out;            // [NN, 64]
  const int* src = ei;
  const int* dst = ei + NE;

  // ws (4B units): cntp[NN*16] | col[NN*CAP] | yh[NN*32] | zh[NN*32] | wbf[8192]
  size_t o_cntp = 0;
  size_t o_col  = o_cntp + (size_t)NN * CSTRIDE;
  size_t o_yh   = o_col + (size_t)NN * CAP;
  size_t o_zh   = o_yh + (size_t)NN * (FDIM / 2);
  size_t o_wbf  = o_zh + (size_t)NN * (FDIM / 2);
  size_t need   = (o_wbf + 8192) * 4;        // ~25.7 MB
  if (ws_size < need || d_ws == nullptr) return;  // fail loudly, never OOB

  int* cntp          = (int*)d_ws + o_cntp;
  int* col           = (int*)d_ws + o_col;
  unsigned short* yh = (unsigned short*)((float*)d_ws + o_yh);
  unsigned short* zh = (unsigned short*)((float*)d_ws + o_zh);
  unsigned short* wbf= (unsigned short*)((float*)d_ws + o_wbf);

  // 1. zero cntp + W->bf16
  init_kernel<<<3189, 256, 0, stream>>>(cntp, W, wbf);
  // 2. fused: scatter (cntp, col)  ||  raw gemm: yh = bf16(x @ W^T)
  fused_kernel<<<SCAT_BLKS + GEMM_BLKS, 256, 0, stream>>>(src, dst, cntp, col,
                                                          x, wbf, yh);
  // 3. hop 1: zh = bf16( dinv^2 * (dinv*Y_self + sum dinv_j*Y_j) )
  gather_kernel<0, 1><<<NN / 8, 256, 0, stream>>>((const unsigned*)yh, zh, cntp, col);
  // 4. hop 2: out = dinv * (A+I) zh
  gather_kernel<1, 0><<<NN / 8, 256, 0, stream>>>((const unsigned*)zh, out, cntp, col);
}

// Round 30
// 64.882 us; speedup vs baseline: 1.1517x; 1.0857x over previous
//
#include <hip/hip_runtime.h>

#define NN 50000
#define NE 300000
#define KDIM 256
#define FDIM 64
#define CAP 48              // max degree capacity; P(deg>47)~1e-30 for multinomial(6)
#define CSTRIDE 16          // one counter per 64B line
#define NTILES16 (NN / 16)  // 3125 row-tiles for MFMA gemm
#define SCAT_BLKS ((NE + 255) / 256)          // 1172
#define GEMM_BLKS ((NTILES16 + 1) / 2)        // 1563
#define FUSE_BLKS (SCAT_BLKS + GEMM_BLKS)     // 2735 = 7*390 + 5

typedef __attribute__((ext_vector_type(8))) short bf16x8;
typedef __attribute__((ext_vector_type(4))) float f32x4;

static __device__ __forceinline__ unsigned short bf16_of(float f) {
  union { float f; unsigned u; } v; v.f = f;
  unsigned r = (v.u + 0x7fffu + ((v.u >> 16) & 1u)) >> 16;  // RTNE
  return (unsigned short)r;
}
static __device__ __forceinline__ void unpack2(unsigned u, float& lo, float& hi) {
  union { unsigned u; float f; } a, b;
  a.u = u << 16; b.u = u & 0xffff0000u;
  lo = a.f; hi = b.f;
}
static __device__ __forceinline__ unsigned pack2(float lo, float hi) {
  return (unsigned)bf16_of(lo) | ((unsigned)bf16_of(hi) << 16);
}

// async global->LDS, 16B per lane: LDS dest = wave-uniform base + lane*16.
static __device__ __forceinline__ void gload_lds16(const float* g, void* l) {
  __builtin_amdgcn_global_load_lds(
      (const __attribute__((address_space(1))) void*)g,
      (__attribute__((address_space(3))) void*)l, 16, 0, 0);
}

// ---------- init: zero cntp (blocks 0..3124) + W->bf16 (blocks 3125..3188) ----------
__global__ __launch_bounds__(256) void init_kernel(int* __restrict__ cntp,
    const float* __restrict__ W, unsigned short* __restrict__ wbf) {
  int b = blockIdx.x, t = threadIdx.x;
  if (b < 3125) {
    cntp[b * 256 + t] = 0;          // 3125*256 = 800000 = NN*CSTRIDE exactly
  } else {
    int i = (b - 3125) * 256 + t;   // 64 blocks * 256 = 16384 = FDIM*KDIM
    wbf[i] = bf16_of(W[i]);
  }
}

// ---------- fused: scatter || gemm with INTERLEAVED block roles ----------
// R29 insight: with role = (blockIdx < SCAT_BLKS), in-order dispatch runs all
// scatter blocks BEFORE gemm blocks -> fused == serial sum (40us ~ 20+20).
// Interleave 7-block groups {3 scatter, 4 gemm} (3:4 = 1172:1563) so both
// roles are co-resident -> latency-bound scatter overlaps MFMA-bound gemm.
// gemm emits RAW Y = x@W^T (bf16); dinv deferred to hops:
//   out = D^-1/2 (A+I) D^-1 (A+I) D^-1/2 Y.
// C/D: col=lane&15, row=(lane>>4)*4+reg (HW-verified m89).
__global__ __launch_bounds__(256) void fused_kernel(
    const int* __restrict__ src, const int* __restrict__ dst,
    int* __restrict__ cntp, int* __restrict__ col,
    const float* __restrict__ x, const unsigned short* __restrict__ wbf,
    unsigned short* __restrict__ yh) {
  __shared__ float4 xs[4][8][64];            // 32 KB: per-wave x staging
  __shared__ float red[2][16][64];           // 8 KB (K-split reduction)
  const int g = blockIdx.x / 7, r = blockIdx.x % 7;
  bool is_scat;
  int ord;                                   // role-local ordinal
  if (g < 390) {                             // full groups: 3 scat + 4 gemm
    is_scat = (r < 3);
    ord = is_scat ? (g * 3 + r) : (g * 4 + (r - 3));
  } else {                                   // tail group (5 blocks): 2 + 3
    is_scat = (r < 2);
    ord = is_scat ? (1170 + r) : (1560 + (r - 2));
  }
  if (is_scat) {                             // ---- scatter (ord < 1172) ----
    int e = ord * 256 + threadIdx.x;
    if (e < NE) {
      int d = dst[e];
      int pos = atomicAdd(&cntp[d * CSTRIDE], 1);
      if (pos < CAP) col[d * CAP + pos] = src[e];  // guard: never corrupt
    }
    return;                                  // scatter blocks skip all barriers
  }
  // ---- K-split x2 gemm (ord < 1563): waves (2t+kh) own tile t's K-half kh ----
  const int wave = threadIdx.x >> 6, lane = threadIdx.x & 63;
  const int tib = wave >> 1, kh = wave & 1;
  const int tile = ord * 2 + tib;
  const bool valid = (tile < NTILES16);
  const int m = lane & 15, kg = lane >> 4;
  const int r0 = tile * 16;
  const float* xr = x + (size_t)((valid ? r0 : 0) + m) * KDIM + kh * 128 + kg * 8;
  const unsigned short* w0 = wbf + (size_t)m * KDIM + kh * 128 + kg * 8;

  #pragma unroll
  for (int j = 0; j < 8; ++j)                // 8 async 1KB stages, zero VGPRs
    gload_lds16(xr + (j >> 1) * 32 + (j & 1) * 4, &xs[wave][j][0]);
  __syncthreads();                           // vmcnt(0) drain -> xs valid

  f32x4 acc0 = {0.f, 0.f, 0.f, 0.f};
  f32x4 acc1 = {0.f, 0.f, 0.f, 0.f};
  f32x4 acc2 = {0.f, 0.f, 0.f, 0.f};
  f32x4 acc3 = {0.f, 0.f, 0.f, 0.f};
  if (valid) {
    #pragma unroll
    for (int kc = 0; kc < 4; ++kc) {
      float4 a0 = xs[wave][2 * kc][lane];    // ds_read_b128, lane's own chunk
      float4 a1 = xs[wave][2 * kc + 1][lane];
      bf16x8 af;
      af[0] = bf16_of(a0.x); af[1] = bf16_of(a0.y);
      af[2] = bf16_of(a0.z); af[3] = bf16_of(a0.w);
      af[4] = bf16_of(a1.x); af[5] = bf16_of(a1.y);
      af[6] = bf16_of(a1.z); af[7] = bf16_of(a1.w);
      bf16x8 b0 = *(const bf16x8*)(w0 + 0 * 16 * KDIM + kc * 32);
      bf16x8 b1 = *(const bf16x8*)(w0 + 1 * 16 * KDIM + kc * 32);
      bf16x8 b2 = *(const bf16x8*)(w0 + 2 * 16 * KDIM + kc * 32);
      bf16x8 b3 = *(const bf16x8*)(w0 + 3 * 16 * KDIM + kc * 32);
      acc0 = __builtin_amdgcn_mfma_f32_16x16x32_bf16(af, b0, acc0, 0, 0, 0);
      acc1 = __builtin_amdgcn_mfma_f32_16x16x32_bf16(af, b1, acc1, 0, 0, 0);
      acc2 = __builtin_amdgcn_mfma_f32_16x16x32_bf16(af, b2, acc2, 0, 0, 0);
      acc3 = __builtin_amdgcn_mfma_f32_16x16x32_bf16(af, b3, acc3, 0, 0, 0);
    }
  }
  if (valid && kh == 1) {
    #pragma unroll
    for (int j = 0; j < 4; ++j) {
      red[tib][0 + j][lane]  = acc0[j];
      red[tib][4 + j][lane]  = acc1[j];
      red[tib][8 + j][lane]  = acc2[j];
      red[tib][12 + j][lane] = acc3[j];
    }
  }
  __syncthreads();
  if (valid && kh == 0) {
    #pragma unroll
    for (int j = 0; j < 4; ++j) {
      acc0[j] += red[tib][0 + j][lane];
      acc1[j] += red[tib][4 + j][lane];
      acc2[j] += red[tib][8 + j][lane];
      acc3[j] += red[tib][12 + j][lane];
    }
    const int m4 = kg * 4;
    #pragma unroll
    for (int r2 = 0; r2 < 4; ++r2) {
      size_t rowoff = (size_t)(r0 + m4 + r2) * FDIM + m;
      yh[rowoff + 0]  = bf16_of(acc0[r2]);   // RAW Y (no dinv)
      yh[rowoff + 16] = bf16_of(acc1[r2]);
      yh[rowoff + 32] = bf16_of(acc2[r2]);
      yh[rowoff + 48] = bf16_of(acc3[r2]);
    }
  }
}

// ---------- gather hop over bf16 rows (128B): 2 nodes/wave, 32 lanes x uint ----------
// Degrees read directly from padded cntp[i*CSTRIDE]. NBRNORM=1 (hop 1):
//   u_i = dinv_i^2 * ( dinv_i*Y_i + sum_j dinv_j*Y_j )
// NBRNORM=0 (hop 2): out_i = dinv_i * ( u_i + sum_j u_j )
// fp32 accumulation; masked 4-batches (OOB multiplier/value zeroed by cndmask).
template <int OUT32, int NBRNORM>
__global__ __launch_bounds__(256) void gather_kernel(const unsigned* __restrict__ inu,
    void* __restrict__ outp, const int* __restrict__ cntp,
    const int* __restrict__ col) {
  int wave = threadIdx.x >> 6, lane = threadIdx.x & 63;
  int half = lane >> 5, hl = lane & 31;
  int node = blockIdx.x * 8 + wave * 2 + half;          // 6250*8 = 50000 exact
  int deg = cntp[node * CSTRIDE];
  int n = min(deg, CAP);
  int sbase = lane & 32;                                // half*32
  float fdeg = (float)deg + 1.0f;
  float di = rsqrtf(fdeg);
  float selfm = NBRNORM ? di : 1.0f;
  float ax, ay;
  unpack2(inu[(size_t)node * 32 + hl], ax, ay);         // self-loop
  ax *= selfm; ay *= selfm;
  float bx = 0.f, by = 0.f, cx = 0.f, cy = 0.f, dx = 0.f, dy = 0.f;
  for (int base = 0; base < n; base += 32) {
    int mB = min(32, n - base);
    int idx = 0; float dvl = 0.f;
    if (hl < mB) {
      idx = col[node * CAP + base + hl];
      if (NBRNORM) dvl = rsqrtf((float)cntp[idx * CSTRIDE] + 1.0f);
    }
    for (int j = 0; j < mB; j += 4) {
      int c0 = __shfl(idx, sbase + j + 0);
      int c1 = __shfl(idx, sbase + j + 1);
      int c2 = __shfl(idx, sbase + j + 2);
      int c3 = __shfl(idx, sbase + j + 3);
      unsigned u0 = inu[(size_t)c0 * 32 + hl];
      unsigned u1 = inu[(size_t)c1 * 32 + hl];
      unsigned u2 = inu[(size_t)c2 * 32 + hl];
      unsigned u3 = inu[(size_t)c3 * 32 + hl];
      float lx, hy;
      if (NBRNORM) {
        float f0 = __shfl(dvl, sbase + j + 0);
        float f1 = __shfl(dvl, sbase + j + 1);
        float f2 = __shfl(dvl, sbase + j + 2);
        float f3 = __shfl(dvl, sbase + j + 3);
        f1 = (j + 1 < mB) ? f1 : 0.f;                   // mask the multiplier
        f2 = (j + 2 < mB) ? f2 : 0.f;
        f3 = (j + 3 < mB) ? f3 : 0.f;
        unpack2(u0, lx, hy); ax = fmaf(lx, f0, ax); ay = fmaf(hy, f0, ay);
        unpack2(u1, lx, hy); bx = fmaf(lx, f1, bx); by = fmaf(hy, f1, by);
        unpack2(u2, lx, hy); cx = fmaf(lx, f2, cx); cy = fmaf(hy, f2, cy);
        unpack2(u3, lx, hy); dx = fmaf(lx, f3, dx); dy = fmaf(hy, f3, dy);
      } else {
        u1 = (j + 1 < mB) ? u1 : 0u;                    // mask the value
        u2 = (j + 2 < mB) ? u2 : 0u;
        u3 = (j + 3 < mB) ? u3 : 0u;
        unpack2(u0, lx, hy); ax += lx; ay += hy;
        unpack2(u1, lx, hy); bx += lx; by += hy;
        unpack2(u2, lx, hy); cx += lx; cy += hy;
        unpack2(u3, lx, hy); dx += lx; dy += hy;
      }
    }
  }
  float s = NBRNORM ? (1.0f / fdeg) : di;               // dinv^2 : dinv
  float rx = (ax + bx + cx + dx) * s;
  float ry = (ay + by + cy + dy) * s;
  if (OUT32) {
    float2 r; r.x = rx; r.y = ry;
    ((float2*)outp)[(size_t)node * 32 + hl] = r;        // fp32 row = 32 float2
  } else {
    ((unsigned*)outp)[(size_t)node * 32 + hl] = pack2(rx, ry);  // bf16 row
  }
}

extern "C" void kernel_launch(void* const* d_in, const int* in_sizes, int n_in,
                              void* d_out, int out_size, void* d_ws, size_t ws_size,
                              hipStream_t stream) {
  const float* x = (const float*)d_in[0];    // [NN, 256]
  const int* ei  = (const int*)d_in[1];      // [2, NE]
  const float* W = (const float*)d_in[2];    // [64, 256]
  float* out     = (float*)d_out;            // [NN, 64]
  const int* src = ei;
  const int* dst = ei + NE;

  // ws (4B units): cntp[NN*16] | col[NN*CAP] | yh[NN*32] | zh[NN*32] | wbf[8192]
  size_t o_cntp = 0;
  size_t o_col  = o_cntp + (size_t)NN * CSTRIDE;
  size_t o_yh   = o_col + (size_t)NN * CAP;
  size_t o_zh   = o_yh + (size_t)NN * (FDIM / 2);
  size_t o_wbf  = o_zh + (size_t)NN * (FDIM / 2);
  size_t need   = (o_wbf + 8192) * 4;        // ~25.7 MB
  if (ws_size < need || d_ws == nullptr) return;  // fail loudly, never OOB

  int* cntp          = (int*)d_ws + o_cntp;
  int* col           = (int*)d_ws + o_col;
  unsigned short* yh = (unsigned short*)((float*)d_ws + o_yh);
  unsigned short* zh = (unsigned short*)((float*)d_ws + o_zh);
  unsigned short* wbf= (unsigned short*)((float*)d_ws + o_wbf);

  // 1. zero cntp + W->bf16
  init_kernel<<<3189, 256, 0, stream>>>(cntp, W, wbf);
  // 2. fused scatter||gemm, roles INTERLEAVED 3:4 for true co-residency
  fused_kernel<<<FUSE_BLKS, 256, 0, stream>>>(src, dst, cntp, col, x, wbf, yh);
  // 3. hop 1: zh = bf16( dinv^2 * (dinv*Y_self + sum dinv_j*Y_j) )
  gather_kernel<0, 1><<<NN / 8, 256, 0, stream>>>((const unsigned*)yh, zh, cntp, col);
  // 4. hop 2: out = dinv * (A+I) zh
  gather_kernel<1, 0><<<NN / 8, 256, 0, stream>>>((const unsigned*)zh, out, cntp, col);
}